// Round 7
// baseline (66.301 us; speedup 1.0000x reference)
//
#include <hip/hip_runtime.h>

#define B_   16
#define C_   128
#define N_   2304      // 48*48
#define ZR   256       // 2*C
#define KS   4         // k-splits for gram
#define KPB  (N_/KS)   // 576
#define KC   64        // k per staged chunk (64 bf16 = 8 granules of 16B)
#define NCH  (KPB/KC)  // 9
#define QT   16384     // 128*128 floats per quadrant tile
#define NBLK 256       // gramred grid: all blocks co-resident (<= 1/CU)

typedef __bf16 bf16x8 __attribute__((ext_vector_type(8)));
typedef float  f32x4  __attribute__((ext_vector_type(4)));

struct Ctrl { double sum; unsigned done; unsigned done2; };

__device__ __forceinline__ ushort rne16(float f) {
    unsigned u = __float_as_uint(f);
    return (ushort)((u + 0x7FFFu + ((u >> 16) & 1u)) >> 16);   // RNE bf16
}

// ---------------- kernel 1: norms + normalize + bf16 convert (float4) ----
// grid: B_*2*36 = 1152 blocks, 256 threads. Block = one side (pred/targ),
// one batch, 64 columns. Also zeroes the 16B control block each launch.
__global__ __launch_bounds__(256) void nc_k(const float* __restrict__ pred,
                                            const float* __restrict__ targ,
                                            ushort* __restrict__ Z,
                                            Ctrl* __restrict__ ctrl) {
    int blk  = blockIdx.x;
    int t    = threadIdx.x;
    if (blk == 0 && t == 0) {            // re-init every launch (ws is poisoned)
        ctrl->sum  = 0.0;
        ctrl->done = 0u;
        ctrl->done2 = 0u;
    }
    int b    = blk / 72;
    int rem  = blk % 72;
    int side = rem / 36;
    int n0   = (rem % 36) * 64;
    int g  = t & 15;
    int rc = t >> 4;

    __shared__ float4 rp[16][16];
    __shared__ float4 rq[4][16];
    __shared__ float4 rn4[16];

    const float* src = (side ? targ : pred) + (size_t)b * C_ * N_ + n0 + 4 * g;
    float4 raw[8];
    float4 sq = make_float4(0.f, 0.f, 0.f, 0.f);
#pragma unroll
    for (int i = 0; i < 8; ++i) {
        raw[i] = *(const float4*)(src + (size_t)(rc * 8 + i) * N_);
        sq.x = fmaf(raw[i].x, raw[i].x, sq.x);
        sq.y = fmaf(raw[i].y, raw[i].y, sq.y);
        sq.z = fmaf(raw[i].z, raw[i].z, sq.z);
        sq.w = fmaf(raw[i].w, raw[i].w, sq.w);
    }
    rp[rc][g] = sq;
    __syncthreads();
    if (t < 64) {
        int gg = t & 15, h = t >> 4;
        float4 a0 = rp[h * 4 + 0][gg], a1 = rp[h * 4 + 1][gg];
        float4 a2 = rp[h * 4 + 2][gg], a3 = rp[h * 4 + 3][gg];
        rq[h][gg] = make_float4(a0.x + a1.x + a2.x + a3.x,
                                a0.y + a1.y + a2.y + a3.y,
                                a0.z + a1.z + a2.z + a3.z,
                                a0.w + a1.w + a2.w + a3.w);
    }
    __syncthreads();
    if (t < 16) {
        float4 a0 = rq[0][t], a1 = rq[1][t], a2 = rq[2][t], a3 = rq[3][t];
        float4 s = make_float4(a0.x + a1.x + a2.x + a3.x,
                               a0.y + a1.y + a2.y + a3.y,
                               a0.z + a1.z + a2.z + a3.z,
                               a0.w + a1.w + a2.w + a3.w);
        rn4[t] = make_float4(rsqrtf(fmaxf(s.x, 1e-20f)),
                             rsqrtf(fmaxf(s.y, 1e-20f)),
                             rsqrtf(fmaxf(s.z, 1e-20f)),
                             rsqrtf(fmaxf(s.w, 1e-20f)));
    }
    __syncthreads();
    float4 rr = rn4[g];
    ushort* dst = Z + (size_t)(b * ZR + side * C_) * N_ + n0 + 4 * g;
#pragma unroll
    for (int i = 0; i < 8; ++i) {
        ushort4 pk;
        pk.x = rne16(raw[i].x * rr.x);
        pk.y = rne16(raw[i].y * rr.y);
        pk.z = rne16(raw[i].z * rr.z);
        pk.w = rne16(raw[i].w * rr.w);
        *(ushort4*)(dst + (size_t)(rc * 8 + i) * N_) = pk;   // 8B store
    }
}

// ---------- kernel 2: gram quadrants -> manual barrier -> reduce -> out ----
// grid: exactly NBLK=256 blocks x 256 threads. All blocks co-resident
// (64KB LDS, 1 block/CU => capacity 2/CU, grid <= 256 CUs), so the
// arrive-and-spin barrier always terminates. NOT cooperative launch
// (R5 showed cg::grid().sync() costs ~37us/sync on this platform).
// Phase A: (b,s,q) partial Gram quadrant: q=0 GA=A A^T, q=1 GB=B B^T,
//          q=2 P=B A^T, q=3 PT=A B^T. Plain stores, no init needed.
// Phase B: (b,seg) coalesced float4 reduce of all 4 streams, double acc.
// Finish:  per-block double atomicAdd; last-arriving block writes out.
__global__ __launch_bounds__(256) void gramred_k(const ushort* __restrict__ Z,
                                                 float* __restrict__ Wp,
                                                 Ctrl* __restrict__ ctrl,
                                                 float* __restrict__ out) {
    __shared__ float4 lds[4096];            // 64 KB: 2 dbuf x (A 1024 | B 1024)
    __shared__ double sd[4];
    int blk = blockIdx.x;
    int t   = threadIdx.x;

    // ================= phase A: partial Gram quadrant =================
    {
        int q = blk & 3;
        int s = (blk >> 2) & 3;
        int b = blk >> 4;
        int side_i = (q == 1 || q == 2);    // operand rows -> output rows i
        int side_j = (q == 1 || q == 3);    // operand rows -> output cols j
        bool same = (side_i == side_j);

        int lane = t & 63;
        int w    = t >> 6;
        int wr = (w >> 1) * 64;
        int wc = (w & 1) * 64;

        const ushort* Zb   = Z + (size_t)b * ZR * N_;
        const ushort* srcA = Zb + (size_t)(side_i * C_) * N_;
        const ushort* srcB = Zb + (size_t)(side_j * C_) * N_;
        int Boff = same ? 0 : 1024;

        f32x4 acc[4][4];
#pragma unroll
        for (int m = 0; m < 4; ++m)
#pragma unroll
            for (int n = 0; n < 4; ++n) acc[m][n] = (f32x4){0.f, 0.f, 0.f, 0.f};

        auto stage = [&](int dbuf, int ch) {
            int kc0 = s * KPB + ch * KC;
            float4* base = lds + dbuf * 2048;
#pragma unroll
            for (int it = 0; it < 4; ++it) {
                int r  = it * 32 + (t >> 3);
                int gl = (t & 7) ^ (r & 7);          // involution swizzle
                const ushort* gp = srcA + (size_t)r * N_ + kc0 + gl * 8;
                __builtin_amdgcn_global_load_lds(
                    (const __attribute__((address_space(1))) void*)gp,
                    (__attribute__((address_space(3))) void*)(base + it * 256 + t),
                    16, 0, 0);
            }
            if (!same) {
#pragma unroll
                for (int it = 0; it < 4; ++it) {
                    int r  = it * 32 + (t >> 3);
                    int gl = (t & 7) ^ (r & 7);
                    const ushort* gp = srcB + (size_t)r * N_ + kc0 + gl * 8;
                    __builtin_amdgcn_global_load_lds(
                        (const __attribute__((address_space(1))) void*)gp,
                        (__attribute__((address_space(3))) void*)(base + 1024 + it * 256 + t),
                        16, 0, 0);
                }
            }
        };

        auto compute = [&](int dbuf) {
            const bf16x8* L = (const bf16x8*)(lds + dbuf * 2048);
#pragma unroll
            for (int kk = 0; kk < 2; ++kk) {
                bf16x8 aA[4], aB[4];
                int gl = kk * 4 + (lane >> 4);
#pragma unroll
                for (int m = 0; m < 4; ++m) {
                    int r = wr + m * 16 + (lane & 15);
                    aA[m] = L[r * 8 + (gl ^ (r & 7))];
                }
#pragma unroll
                for (int n = 0; n < 4; ++n) {
                    int r = wc + n * 16 + (lane & 15);
                    aB[n] = L[Boff + r * 8 + (gl ^ (r & 7))];
                }
#pragma unroll
                for (int m = 0; m < 4; ++m)
#pragma unroll
                    for (int n = 0; n < 4; ++n)
                        acc[m][n] = __builtin_amdgcn_mfma_f32_16x16x32_bf16(
                            aA[m], aB[n], acc[m][n], 0, 0, 0);
            }
        };

        stage(0, 0);
        int buf = 0;
        for (int ch = 0; ch < NCH; ++ch) {
            __syncthreads();                // drains vmcnt: chunk ch landed
            if (ch + 1 < NCH) stage(buf ^ 1, ch + 1);
            compute(buf);
            buf ^= 1;
        }

        float* Wq = Wp + ((size_t)((s * B_ + b) * 4 + q) << 14);
#pragma unroll
        for (int m = 0; m < 4; ++m) {
            int row0 = wr + m * 16 + (lane >> 4) * 4;
#pragma unroll
            for (int n = 0; n < 4; ++n) {
                int col = wc + n * 16 + (lane & 15);
#pragma unroll
                for (int v = 0; v < 4; ++v)
                    Wq[(size_t)(row0 + v) * C_ + col] = acc[m][n][v];
            }
        }
    }

    // ============== manual grid barrier (all blocks co-resident) ==========
    __syncthreads();
    if (t == 0) {
        __hip_atomic_fetch_add(&ctrl->done, 1u, __ATOMIC_RELEASE,
                               __HIP_MEMORY_SCOPE_AGENT);
        while (__hip_atomic_load(&ctrl->done, __ATOMIC_ACQUIRE,
                                 __HIP_MEMORY_SCOPE_AGENT) != NBLK)
            __builtin_amdgcn_s_sleep(2);
    }
    __syncthreads();

    // ================= phase B: coalesced float4 reduce =================
    {
        int b   = blk >> 4;
        int seg = blk & 15;
        int idx = seg * 256 + t;            // 0..4095 float4 per stream
        const float4* W4 = (const float4*)Wp;
        float4 ga = make_float4(0.f, 0.f, 0.f, 0.f), gb = ga, p = ga, pt = ga;
#pragma unroll
        for (int s = 0; s < KS; ++s) {
            size_t base = ((size_t)(s * B_ + b) * 4) << 12;   // float4 units
            float4 a0 = W4[base + idx];
            float4 a1 = W4[base + 4096 + idx];
            float4 a2 = W4[base + 8192 + idx];
            float4 a3 = W4[base + 12288 + idx];
            ga.x += a0.x; ga.y += a0.y; ga.z += a0.z; ga.w += a0.w;
            gb.x += a1.x; gb.y += a1.y; gb.z += a1.z; gb.w += a1.w;
            p.x  += a2.x; p.y  += a2.y; p.z  += a2.z; p.w  += a2.w;
            pt.x += a3.x; pt.y += a3.y; pt.z += a3.z; pt.w += a3.w;
        }
        double v = ((double)ga.x * gb.x - (double)p.x * pt.x)
                 + ((double)ga.y * gb.y - (double)p.y * pt.y)
                 + ((double)ga.z * gb.z - (double)p.z * pt.z)
                 + ((double)ga.w * gb.w - (double)p.w * pt.w);
#pragma unroll
        for (int o = 32; o > 0; o >>= 1) v += __shfl_down(v, o, 64);
        if ((t & 63) == 0) sd[t >> 6] = v;
        __syncthreads();
        if (t == 0) {
            double bv = sd[0] + sd[1] + sd[2] + sd[3];
            __hip_atomic_fetch_add(&ctrl->sum, bv, __ATOMIC_RELAXED,
                                   __HIP_MEMORY_SCOPE_AGENT);
            unsigned c = __hip_atomic_fetch_add(&ctrl->done2, 1u,
                                                __ATOMIC_ACQ_REL,
                                                __HIP_MEMORY_SCOPE_AGENT);
            if (c == NBLK - 1) {            // last block: all adds visible
                double tot = __hip_atomic_load(&ctrl->sum, __ATOMIC_ACQUIRE,
                                               __HIP_MEMORY_SCOPE_AGENT);
                out[0] = (float)(2.0 * tot
                                 / ((double)B_ * (double)N_ * (double)N_));
            }
        }
    }
}

extern "C" void kernel_launch(void* const* d_in, const int* in_sizes, int n_in,
                              void* d_out, int out_size, void* d_ws, size_t ws_size,
                              hipStream_t stream) {
    const float* pred = (const float*)d_in[0];
    const float* targ = (const float*)d_in[1];
    float* out = (float*)d_out;

    // workspace layout (bytes):
    //   Z   : B_*ZR*N_*2      = 18,874,368  (bf16, normalized)
    //   Wp  : KS*B_*4*QT*4    = 16,777,216  (fp32 partial quadrants)
    //   ctrl: 16 bytes (double sum, done, done2) -- re-zeroed by nc_k
    char* ws = (char*)d_ws;
    ushort* Z  = (ushort*)ws;
    float*  Wp = (float*)(ws + (size_t)B_ * ZR * N_ * 2);
    Ctrl*   ct = (Ctrl*)(ws + (size_t)B_ * ZR * N_ * 2
                            + (size_t)KS * B_ * 4 * QT * 4);

    nc_k<<<B_ * 2 * 36, 256, 0, stream>>>(pred, targ, Z, ct);
    gramred_k<<<NBLK, 256, 0, stream>>>(Z, Wp, ct, out);
}

// Round 8
// 34.405 us; speedup vs baseline: 1.9271x; 1.9271x over previous
//
#include <hip/hip_runtime.h>

#define B_   16
#define C_   128
#define N_   2304      // 48*48
#define ZR   256       // 2*C
#define KS   4         // k-splits for gram
#define KPB  (N_/KS)   // 576
#define KC   64        // k per staged chunk (64 bf16 = 8 granules of 16B)
#define NCH  (KPB/KC)  // 9
#define QT   16384     // 128*128 elems per quadrant tile
#define NRB  128       // redfin grid

typedef __bf16 bf16x8 __attribute__((ext_vector_type(8)));
typedef float  f32x4  __attribute__((ext_vector_type(4)));

struct Ctrl { double sum; unsigned done2; unsigned pad; };

__device__ __forceinline__ ushort rne16(float f) {
    unsigned u = __float_as_uint(f);
    return (ushort)((u + 0x7FFFu + ((u >> 16) & 1u)) >> 16);   // RNE bf16
}

// ---------------- kernel 1: norms + normalize + bf16 convert (float4) ----
// grid: B_*2*36 = 1152 blocks, 256 threads. Block = one side (pred/targ),
// one batch, 64 columns. Block 0 also re-zeroes the control block (ws is
// poisoned once before timing; kernels must self-initialize state).
__global__ __launch_bounds__(256) void nc_k(const float* __restrict__ pred,
                                            const float* __restrict__ targ,
                                            ushort* __restrict__ Z,
                                            Ctrl* __restrict__ ctrl) {
    int blk  = blockIdx.x;
    int t    = threadIdx.x;
    if (blk == 0 && t == 0) {
        ctrl->sum   = 0.0;
        ctrl->done2 = 0u;
    }
    int b    = blk / 72;
    int rem  = blk % 72;
    int side = rem / 36;
    int n0   = (rem % 36) * 64;
    int g  = t & 15;
    int rc = t >> 4;

    __shared__ float4 rp[16][16];
    __shared__ float4 rq[4][16];
    __shared__ float4 rn4[16];

    const float* src = (side ? targ : pred) + (size_t)b * C_ * N_ + n0 + 4 * g;
    float4 raw[8];
    float4 sq = make_float4(0.f, 0.f, 0.f, 0.f);
#pragma unroll
    for (int i = 0; i < 8; ++i) {
        raw[i] = *(const float4*)(src + (size_t)(rc * 8 + i) * N_);
        sq.x = fmaf(raw[i].x, raw[i].x, sq.x);
        sq.y = fmaf(raw[i].y, raw[i].y, sq.y);
        sq.z = fmaf(raw[i].z, raw[i].z, sq.z);
        sq.w = fmaf(raw[i].w, raw[i].w, sq.w);
    }
    rp[rc][g] = sq;
    __syncthreads();
    if (t < 64) {
        int gg = t & 15, h = t >> 4;
        float4 a0 = rp[h * 4 + 0][gg], a1 = rp[h * 4 + 1][gg];
        float4 a2 = rp[h * 4 + 2][gg], a3 = rp[h * 4 + 3][gg];
        rq[h][gg] = make_float4(a0.x + a1.x + a2.x + a3.x,
                                a0.y + a1.y + a2.y + a3.y,
                                a0.z + a1.z + a2.z + a3.z,
                                a0.w + a1.w + a2.w + a3.w);
    }
    __syncthreads();
    if (t < 16) {
        float4 a0 = rq[0][t], a1 = rq[1][t], a2 = rq[2][t], a3 = rq[3][t];
        float4 s = make_float4(a0.x + a1.x + a2.x + a3.x,
                               a0.y + a1.y + a2.y + a3.y,
                               a0.z + a1.z + a2.z + a3.z,
                               a0.w + a1.w + a2.w + a3.w);
        rn4[t] = make_float4(rsqrtf(fmaxf(s.x, 1e-20f)),
                             rsqrtf(fmaxf(s.y, 1e-20f)),
                             rsqrtf(fmaxf(s.z, 1e-20f)),
                             rsqrtf(fmaxf(s.w, 1e-20f)));
    }
    __syncthreads();
    float4 rr = rn4[g];
    ushort* dst = Z + (size_t)(b * ZR + side * C_) * N_ + n0 + 4 * g;
#pragma unroll
    for (int i = 0; i < 8; ++i) {
        ushort4 pk;
        pk.x = rne16(raw[i].x * rr.x);
        pk.y = rne16(raw[i].y * rr.y);
        pk.z = rne16(raw[i].z * rr.z);
        pk.w = rne16(raw[i].w * rr.w);
        *(ushort4*)(dst + (size_t)(rc * 8 + i) * N_) = pk;   // 8B store
    }
}

// ---------------- kernel 2: partial Gram quadrants via bf16 MFMA ----------
// grid: B_*KS*4 = 256 blocks, 256 threads (4 waves). Block = (batch, ksplit,
// quadrant q): q=0 GA=A A^T, q=1 GB=B B^T, q=2 P=B A^T, q=3 PT=A B^T.
// Epilogue: acc -> LDS (f32, exactly 64KB) -> packed bf16 global (coalesced
// 8B/lane stores). Halves Wp traffic vs fp32; RNE error budget >150x margin.
__global__ __launch_bounds__(256) void gram_k(const ushort* __restrict__ Z,
                                              ushort* __restrict__ Wp) {
    int blk = blockIdx.x;
    int q = blk & 3;
    int s = (blk >> 2) & 3;
    int b = blk >> 4;
    int side_i = (q == 1 || q == 2);    // operand rows -> output rows i
    int side_j = (q == 1 || q == 3);    // operand rows -> output cols j
    bool same = (side_i == side_j);

    int t    = threadIdx.x;
    int lane = t & 63;
    int w    = t >> 6;
    int wr = (w >> 1) * 64;
    int wc = (w & 1) * 64;

    __shared__ float4 lds[4096];            // 64 KB: 2 dbuf x (A 1024 | B 1024)

    const ushort* Zb   = Z + (size_t)b * ZR * N_;
    const ushort* srcA = Zb + (size_t)(side_i * C_) * N_;
    const ushort* srcB = Zb + (size_t)(side_j * C_) * N_;
    int Boff = same ? 0 : 1024;

    f32x4 acc[4][4];
#pragma unroll
    for (int m = 0; m < 4; ++m)
#pragma unroll
        for (int n = 0; n < 4; ++n) acc[m][n] = (f32x4){0.f, 0.f, 0.f, 0.f};

    auto stage = [&](int dbuf, int ch) {
        int kc0 = s * KPB + ch * KC;
        float4* base = lds + dbuf * 2048;
#pragma unroll
        for (int it = 0; it < 4; ++it) {
            int r  = it * 32 + (t >> 3);
            int gl = (t & 7) ^ (r & 7);          // involution swizzle
            const ushort* gp = srcA + (size_t)r * N_ + kc0 + gl * 8;
            __builtin_amdgcn_global_load_lds(
                (const __attribute__((address_space(1))) void*)gp,
                (__attribute__((address_space(3))) void*)(base + it * 256 + t),
                16, 0, 0);
        }
        if (!same) {
#pragma unroll
            for (int it = 0; it < 4; ++it) {
                int r  = it * 32 + (t >> 3);
                int gl = (t & 7) ^ (r & 7);
                const ushort* gp = srcB + (size_t)r * N_ + kc0 + gl * 8;
                __builtin_amdgcn_global_load_lds(
                    (const __attribute__((address_space(1))) void*)gp,
                    (__attribute__((address_space(3))) void*)(base + 1024 + it * 256 + t),
                    16, 0, 0);
            }
        }
    };

    auto compute = [&](int dbuf) {
        const bf16x8* L = (const bf16x8*)(lds + dbuf * 2048);
#pragma unroll
        for (int kk = 0; kk < 2; ++kk) {
            bf16x8 aA[4], aB[4];
            int gl = kk * 4 + (lane >> 4);
#pragma unroll
            for (int m = 0; m < 4; ++m) {
                int r = wr + m * 16 + (lane & 15);
                aA[m] = L[r * 8 + (gl ^ (r & 7))];
            }
#pragma unroll
            for (int n = 0; n < 4; ++n) {
                int r = wc + n * 16 + (lane & 15);
                aB[n] = L[Boff + r * 8 + (gl ^ (r & 7))];
            }
#pragma unroll
            for (int m = 0; m < 4; ++m)
#pragma unroll
                for (int n = 0; n < 4; ++n)
                    acc[m][n] = __builtin_amdgcn_mfma_f32_16x16x32_bf16(
                        aA[m], aB[n], acc[m][n], 0, 0, 0);
        }
    };

    stage(0, 0);
    int buf = 0;
    for (int ch = 0; ch < NCH; ++ch) {
        __syncthreads();                    // drains vmcnt: chunk ch landed
        if (ch + 1 < NCH) stage(buf ^ 1, ch + 1);
        compute(buf);
        buf ^= 1;
    }

    // ---- epilogue: acc -> LDS f32 (128x128 = 64KB exactly) -> bf16 global ----
    __syncthreads();                        // all waves done reading lds
    float* Lf = (float*)lds;
#pragma unroll
    for (int m = 0; m < 4; ++m) {
        int row0 = wr + m * 16 + (lane >> 4) * 4;
#pragma unroll
        for (int n = 0; n < 4; ++n) {
            int col = wc + n * 16 + (lane & 15);
#pragma unroll
            for (int v = 0; v < 4; ++v)
                Lf[(size_t)(row0 + v) * C_ + col] = acc[m][n][v];
        }
    }
    __syncthreads();
    ushort* Wq = Wp + (size_t)((s * B_ + b) * 4 + q) * QT;
    const float4* L4 = (const float4*)lds;
#pragma unroll
    for (int i = 0; i < 16; ++i) {          // strided read: 2-way LDS (free)
        float4 qv = L4[i * 256 + t];
        ushort4 pk;
        pk.x = rne16(qv.x);
        pk.y = rne16(qv.y);
        pk.z = rne16(qv.z);
        pk.w = rne16(qv.w);
        *(ushort4*)(Wq + i * 1024 + 4 * t) = pk;   // 8B/lane, coalesced
    }
}

// ------------- kernel 3: reduce + finalize (tail atomics, no spin) -------
// grid: NRB=128 blocks (16 b x 8 seg), 256 threads. Coalesced uint4 loads of
// all 4 bf16 streams; f32 split-sum; double elementwise contraction; block
// partial -> RELAXED sum-add + RELEASE counter; winner ACQUIRE-RMWs the sum
// and writes out. No mid-kernel barrier (R5/R7: grid sync costs 40-70us).
__global__ __launch_bounds__(256) void redfin_k(const ushort* __restrict__ Wp,
                                                Ctrl* __restrict__ ctrl,
                                                float* __restrict__ out) {
    int blk = blockIdx.x;
    int b   = blk >> 3;
    int seg = blk & 7;
    int t   = threadIdx.x;

    const uint4* W4 = (const uint4*)Wp;
    float ga[8], gb[8], p[8], pt[8];
#pragma unroll
    for (int e = 0; e < 8; ++e) { ga[e] = gb[e] = p[e] = pt[e] = 0.f; }

#pragma unroll
    for (int s = 0; s < KS; ++s) {
        size_t base = (size_t)((s * B_ + b) * 4) * 2048 + seg * 256 + t;
        uint4 a0 = W4[base];                // GA: 8 bf16 vals
        uint4 a1 = W4[base + 2048];         // GB
        uint4 a2 = W4[base + 4096];         // P
        uint4 a3 = W4[base + 6144];         // PT
        const unsigned* u0 = (const unsigned*)&a0;
        const unsigned* u1 = (const unsigned*)&a1;
        const unsigned* u2 = (const unsigned*)&a2;
        const unsigned* u3 = (const unsigned*)&a3;
#pragma unroll
        for (int h = 0; h < 4; ++h) {
            ga[2 * h]     += __uint_as_float(u0[h] << 16);
            ga[2 * h + 1] += __uint_as_float(u0[h] & 0xFFFF0000u);
            gb[2 * h]     += __uint_as_float(u1[h] << 16);
            gb[2 * h + 1] += __uint_as_float(u1[h] & 0xFFFF0000u);
            p[2 * h]      += __uint_as_float(u2[h] << 16);
            p[2 * h + 1]  += __uint_as_float(u2[h] & 0xFFFF0000u);
            pt[2 * h]     += __uint_as_float(u3[h] << 16);
            pt[2 * h + 1] += __uint_as_float(u3[h] & 0xFFFF0000u);
        }
    }
    double v = 0.0;
#pragma unroll
    for (int e = 0; e < 8; ++e)
        v += (double)ga[e] * (double)gb[e] - (double)p[e] * (double)pt[e];

    __shared__ double sd[4];
#pragma unroll
    for (int o = 32; o > 0; o >>= 1) v += __shfl_down(v, o, 64);
    if ((t & 63) == 0) sd[t >> 6] = v;
    __syncthreads();
    if (t == 0) {
        double bv = sd[0] + sd[1] + sd[2] + sd[3];
        __hip_atomic_fetch_add(&ctrl->sum, bv, __ATOMIC_RELAXED,
                               __HIP_MEMORY_SCOPE_AGENT);
        unsigned c = __hip_atomic_fetch_add(&ctrl->done2, 1u, __ATOMIC_RELEASE,
                                            __HIP_MEMORY_SCOPE_AGENT);
        if (c == NRB - 1) {                 // last block: read via atomic path
            double tot = __hip_atomic_fetch_add(&ctrl->sum, 0.0,
                                                __ATOMIC_ACQUIRE,
                                                __HIP_MEMORY_SCOPE_AGENT);
            out[0] = (float)(2.0 * tot
                             / ((double)B_ * (double)N_ * (double)N_));
        }
    }
}

extern "C" void kernel_launch(void* const* d_in, const int* in_sizes, int n_in,
                              void* d_out, int out_size, void* d_ws, size_t ws_size,
                              hipStream_t stream) {
    const float* pred = (const float*)d_in[0];
    const float* targ = (const float*)d_in[1];
    float* out = (float*)d_out;

    // workspace layout (bytes):
    //   Z   : B_*ZR*N_*2      = 18,874,368  (bf16, normalized)
    //   Wp  : KS*B_*4*QT*2    =  8,388,608  (bf16 partial quadrants)
    //   ctrl: 16 bytes (double sum, done2) -- re-zeroed by nc_k each launch
    char*   ws = (char*)d_ws;
    ushort* Z  = (ushort*)ws;
    ushort* Wp = (ushort*)(ws + (size_t)B_ * ZR * N_ * 2);
    Ctrl*   ct = (Ctrl*)(ws + (size_t)B_ * ZR * N_ * 2
                            + (size_t)KS * B_ * 4 * QT * 2);

    nc_k<<<B_ * 2 * 36, 256, 0, stream>>>(pred, targ, Z, ct);
    gram_k<<<B_ * KS * 4, 256, 0, stream>>>(Z, Wp);
    redfin_k<<<NRB, 256, 0, stream>>>(Wp, ct, out);
}